// Round 1
// baseline (1055.221 us; speedup 1.0000x reference)
//
#include <hip/hip_runtime.h>
#include <math.h>

// Problem constants (B,T,D,H from reference)
#define NB 4
#define NT 2048
#define ND 512
#define NH 8
#define NC 64
#define NM (NB*NT)          // 8192 rows
#define LN_EPS 1e-5f

// ---------------------------------------------------------------------------
// Kernel 1: LayerNorm over last dim (D=512). One block (256 thr) per row.
// ---------------------------------------------------------------------------
__global__ __launch_bounds__(256) void ln_kernel(const float* __restrict__ x,
        const float* __restrict__ gamma, const float* __restrict__ beta,
        float* __restrict__ xn) {
    const int row = blockIdx.x;
    const float* xr = x + (size_t)row * ND;
    float* outr = xn + (size_t)row * ND;
    const int t = threadIdx.x;

    float2 v = *(const float2*)(xr + 2*t);
    float s  = v.x + v.y;
    float ss = v.x*v.x + v.y*v.y;
    #pragma unroll
    for (int off = 1; off < 64; off <<= 1) {
        s  += __shfl_xor(s, off);
        ss += __shfl_xor(ss, off);
    }
    __shared__ float sb[4], ssb[4];
    if ((t & 63) == 0) { sb[t >> 6] = s; ssb[t >> 6] = ss; }
    __syncthreads();
    s  = sb[0] + sb[1] + sb[2] + sb[3];
    ss = ssb[0] + ssb[1] + ssb[2] + ssb[3];

    const float mu   = s * (1.0f / ND);
    const float var  = ss * (1.0f / ND) - mu * mu;
    const float rstd = rsqrtf(var + LN_EPS);

    float2 g  = *(const float2*)(gamma + 2*t);
    float2 be = *(const float2*)(beta + 2*t);
    float2 o;
    o.x = (v.x - mu) * rstd * g.x + be.x;
    o.y = (v.y - mu) * rstd * g.y + be.y;
    *(float2*)(outr + 2*t) = o;
}

// ---------------------------------------------------------------------------
// Kernel 2: q/k/v = xn @ W^T.  C[m][n] = sum_k xn[m][k] * W[n][k].
// 64x64x16 tiles, fp32, LDS staged transposed (As[k][m]) so compute reads are
// aligned float4 (ds_read_b128).  blockIdx.z selects {Wq,Wk,Wv}.
// ---------------------------------------------------------------------------
__global__ __launch_bounds__(256) void qkv_gemm(const float* __restrict__ xn,
        const float* __restrict__ Wq, const float* __restrict__ Wk,
        const float* __restrict__ Wv,
        float* __restrict__ qo, float* __restrict__ ko, float* __restrict__ vo) {
    const float* W; float* outp;
    if (blockIdx.z == 0)      { W = Wq; outp = qo; }
    else if (blockIdx.z == 1) { W = Wk; outp = ko; }
    else                      { W = Wv; outp = vo; }

    const int bm = blockIdx.y * 64;
    const int bn = blockIdx.x * 64;
    const int t  = threadIdx.x;

    __shared__ float As[16][64];   // [k][m]
    __shared__ float Bs[16][64];   // [k][n]

    float acc[4][4] = {};
    const int tm = 4 * (t >> 4);   // C rows (broadcast reads)
    const int tn = 4 * (t & 15);   // C cols (coalesced writes)
    const int lr = t >> 2;         // staging row 0..63
    const int lc = 4 * (t & 3);    // staging k-offset 0..12

    for (int k0 = 0; k0 < ND; k0 += 16) {
        float4 a4 = *(const float4*)(xn + (size_t)(bm + lr) * ND + k0 + lc);
        float4 b4 = *(const float4*)(W  + (size_t)(bn + lr) * ND + k0 + lc);
        __syncthreads();
        As[lc+0][lr] = a4.x; As[lc+1][lr] = a4.y; As[lc+2][lr] = a4.z; As[lc+3][lr] = a4.w;
        Bs[lc+0][lr] = b4.x; Bs[lc+1][lr] = b4.y; Bs[lc+2][lr] = b4.z; Bs[lc+3][lr] = b4.w;
        __syncthreads();
        #pragma unroll
        for (int kk = 0; kk < 16; ++kk) {
            float4 av = *(const float4*)&As[kk][tm];
            float4 bv = *(const float4*)&Bs[kk][tn];
            float a[4] = {av.x, av.y, av.z, av.w};
            float b[4] = {bv.x, bv.y, bv.z, bv.w};
            #pragma unroll
            for (int i = 0; i < 4; ++i)
                #pragma unroll
                for (int j = 0; j < 4; ++j)
                    acc[i][j] += a[i] * b[j];
        }
    }
    #pragma unroll
    for (int i = 0; i < 4; ++i) {
        float4 ov = make_float4(acc[i][0], acc[i][1], acc[i][2], acc[i][3]);
        *(float4*)(outp + (size_t)(bm + tm + i) * ND + bn + tn) = ov;
    }
}

// ---------------------------------------------------------------------------
// Kernel 3: flash-style attention per (b, h, 64-query tile) + fused epilogue
// out = x + emb + softmax(QK^T/8) V.
// LDS tiles stride 65 -> conflict-free column reads.  PV uses shfl broadcast
// of P (no P buffer in LDS).
// ---------------------------------------------------------------------------
#define ATT_S 65

__global__ __launch_bounds__(256) void attn_kernel(
        const float* __restrict__ q, const float* __restrict__ k,
        const float* __restrict__ v, const float* __restrict__ x,
        const float* __restrict__ emb, float* __restrict__ out) {
    const int b  = blockIdx.z;
    const int h  = blockIdx.y;
    const int q0 = blockIdx.x * 64;
    const int t  = threadIdx.x;

    __shared__ float Qs[64][ATT_S];
    __shared__ float Ks[64][ATT_S];
    __shared__ float Vs[64][ATT_S];

    const size_t hbase = (size_t)b * NT * ND + (size_t)h * NC;

    // stage Q tile (64 rows x 64 cols)
    #pragma unroll
    for (int it = 0; it < 4; ++it) {
        int idx = it * 256 + t;
        int r   = idx >> 4;
        int c4  = (idx & 15) << 2;
        float4 a4 = *(const float4*)(q + hbase + (size_t)(q0 + r) * ND + c4);
        Qs[r][c4+0] = a4.x; Qs[r][c4+1] = a4.y; Qs[r][c4+2] = a4.z; Qs[r][c4+3] = a4.w;
    }

    float m_i[4], l_i[4], o[4][4];
    #pragma unroll
    for (int i = 0; i < 4; ++i) {
        m_i[i] = -1e30f; l_i[i] = 0.f;
        #pragma unroll
        for (int j = 0; j < 4; ++j) o[i][j] = 0.f;
    }

    const int qrow = 4 * (t >> 4);   // 4 query rows per thread
    const int kcol = 4 * (t & 15);   // 4 key cols (S phase) / channels (PV phase)
    const int lane = t & 63;
    const float scale = 0.125f;      // 1/sqrt(64)

    for (int kt = 0; kt < NT; kt += 64) {
        __syncthreads();
        #pragma unroll
        for (int it = 0; it < 4; ++it) {
            int idx = it * 256 + t;
            int r   = idx >> 4;
            int c4  = (idx & 15) << 2;
            float4 kv = *(const float4*)(k + hbase + (size_t)(kt + r) * ND + c4);
            float4 vv = *(const float4*)(v + hbase + (size_t)(kt + r) * ND + c4);
            Ks[r][c4+0] = kv.x; Ks[r][c4+1] = kv.y; Ks[r][c4+2] = kv.z; Ks[r][c4+3] = kv.w;
            Vs[r][c4+0] = vv.x; Vs[r][c4+1] = vv.y; Vs[r][c4+2] = vv.z; Vs[r][c4+3] = vv.w;
        }
        __syncthreads();

        // S = (Q K^T) — 4x4 per thread
        float s[4][4] = {};
        #pragma unroll 4
        for (int c = 0; c < NC; ++c) {
            float a[4], bb[4];
            #pragma unroll
            for (int i = 0; i < 4; ++i) a[i] = Qs[qrow + i][c];
            #pragma unroll
            for (int j = 0; j < 4; ++j) bb[j] = Ks[kcol + j][c];
            #pragma unroll
            for (int i = 0; i < 4; ++i)
                #pragma unroll
                for (int j = 0; j < 4; ++j)
                    s[i][j] += a[i] * bb[j];
        }

        // online softmax (row groups = 16 lanes sharing qrow)
        #pragma unroll
        for (int i = 0; i < 4; ++i) {
            float tm = -1e30f;
            #pragma unroll
            for (int j = 0; j < 4; ++j) { s[i][j] *= scale; tm = fmaxf(tm, s[i][j]); }
            #pragma unroll
            for (int off = 1; off < 16; off <<= 1) tm = fmaxf(tm, __shfl_xor(tm, off));
            float nm = fmaxf(m_i[i], tm);
            float fs = __expf(m_i[i] - nm);
            m_i[i] = nm;
            float ts = 0.f;
            #pragma unroll
            for (int j = 0; j < 4; ++j) { s[i][j] = __expf(s[i][j] - nm); ts += s[i][j]; }
            #pragma unroll
            for (int off = 1; off < 16; off <<= 1) ts += __shfl_xor(ts, off);
            l_i[i] = l_i[i] * fs + ts;
            #pragma unroll
            for (int j = 0; j < 4; ++j) o[i][j] *= fs;
        }

        // O += P V : broadcast P across the 16-lane row group via shfl
        #pragma unroll 2
        for (int sidx = 0; sidx < 16; ++sidx) {
            const int src = (lane & 48) + sidx;
            #pragma unroll
            for (int jj = 0; jj < 4; ++jj) {
                float pb[4];
                #pragma unroll
                for (int i = 0; i < 4; ++i) pb[i] = __shfl(s[i][jj], src);
                const int kk = 4 * sidx + jj;
                float vv[4];
                #pragma unroll
                for (int j = 0; j < 4; ++j) vv[j] = Vs[kk][kcol + j];
                #pragma unroll
                for (int i = 0; i < 4; ++i)
                    #pragma unroll
                    for (int j = 0; j < 4; ++j)
                        o[i][j] += pb[i] * vv[j];
            }
        }
    }

    // epilogue: out = x + emb + O/l
    float4 ev = *(const float4*)(emb + (size_t)b * ND + h * NC + kcol);
    #pragma unroll
    for (int i = 0; i < 4; ++i) {
        float inv = 1.0f / l_i[i];
        size_t ridx = hbase + (size_t)(q0 + qrow + i) * ND + kcol;
        float4 xv = *(const float4*)(x + ridx);
        float4 ov;
        ov.x = xv.x + ev.x + o[i][0] * inv;
        ov.y = xv.y + ev.y + o[i][1] * inv;
        ov.z = xv.z + ev.z + o[i][2] * inv;
        ov.w = xv.w + ev.w + o[i][3] * inv;
        *(float4*)(out + ridx) = ov;
    }
}

// ---------------------------------------------------------------------------
extern "C" void kernel_launch(void* const* d_in, const int* in_sizes, int n_in,
                              void* d_out, int out_size, void* d_ws, size_t ws_size,
                              hipStream_t stream) {
    const float* x     = (const float*)d_in[0];
    const float* emb   = (const float*)d_in[1];
    const float* Wq    = (const float*)d_in[2];
    const float* Wk    = (const float*)d_in[3];
    const float* Wv    = (const float*)d_in[4];
    const float* gamma = (const float*)d_in[5];
    const float* beta  = (const float*)d_in[6];
    float* out = (float*)d_out;

    // xn lives in d_out (exactly M*D floats, fully overwritten by attention).
    // q,k,v in workspace: 3 * 8192*512*4B = 48 MB.
    float* xn = out;
    float* qb = (float*)d_ws;
    float* kb = qb + (size_t)NM * ND;
    float* vb = kb + (size_t)NM * ND;

    ln_kernel<<<NM, 256, 0, stream>>>(x, gamma, beta, xn);

    dim3 g2(ND / 64, NM / 64, 3);
    qkv_gemm<<<g2, 256, 0, stream>>>(xn, Wq, Wk, Wv, qb, kb, vb);

    dim3 g3(NT / 64, NH, NB);
    attn_kernel<<<g3, 256, 0, stream>>>(qb, kb, vb, x, emb, out);
}

// Round 2
// 156.824 us; speedup vs baseline: 6.7287x; 6.7287x over previous
//
#include <hip/hip_runtime.h>
#include <math.h>

#define NB 4
#define NT 2048
#define ND 512
#define NH 8
#define NC 64
#define NM (NB*NT)
#define LN_EPS 1e-5f
#define SCL 0.18033688f   // (1/sqrt(64)) * log2(e)

typedef __attribute__((ext_vector_type(8))) short bf16x8;
typedef __attribute__((ext_vector_type(4))) float f32x4;

__device__ inline unsigned short f2b(float f) {
    unsigned int u = __builtin_bit_cast(unsigned int, f);
    u += 0x7FFFu + ((u >> 16) & 1u);
    return (unsigned short)(u >> 16);
}

__device__ inline void gload_lds16(const void* g, void* l) {
    __builtin_amdgcn_global_load_lds(
        (__attribute__((address_space(1))) void*)g,
        (__attribute__((address_space(3))) void*)l, 16, 0, 0);
}

// ---------------------------------------------------------------------------
// LayerNorm -> bf16 xn.  One 256-thr block per row (D=512).
// ---------------------------------------------------------------------------
__global__ __launch_bounds__(256) void ln_kernel(const float* __restrict__ x,
        const float* __restrict__ gamma, const float* __restrict__ beta,
        unsigned short* __restrict__ xb) {
    const int row = blockIdx.x;
    const float* xr = x + (size_t)row * ND;
    const int t = threadIdx.x;

    float2 v = *(const float2*)(xr + 2*t);
    float s  = v.x + v.y;
    float ss = v.x*v.x + v.y*v.y;
    #pragma unroll
    for (int off = 1; off < 64; off <<= 1) {
        s  += __shfl_xor(s, off);
        ss += __shfl_xor(ss, off);
    }
    __shared__ float sb[4], ssb[4];
    if ((t & 63) == 0) { sb[t >> 6] = s; ssb[t >> 6] = ss; }
    __syncthreads();
    s  = sb[0] + sb[1] + sb[2] + sb[3];
    ss = ssb[0] + ssb[1] + ssb[2] + ssb[3];

    const float mu   = s * (1.0f / ND);
    const float var  = ss * (1.0f / ND) - mu * mu;
    const float rstd = rsqrtf(var + LN_EPS);

    float2 g  = *(const float2*)(gamma + 2*t);
    float2 be = *(const float2*)(beta + 2*t);
    ushort2 o;
    o.x = f2b((v.x - mu) * rstd * g.x + be.x);
    o.y = f2b((v.y - mu) * rstd * g.y + be.y);
    *(ushort2*)(xb + (size_t)row * ND + 2*t) = o;
}

// ---------------------------------------------------------------------------
// W fp32 -> bf16 (3 matrices into one contiguous buffer)
// ---------------------------------------------------------------------------
__global__ __launch_bounds__(256) void wconv_kernel(const float* __restrict__ Wq,
        const float* __restrict__ Wk, const float* __restrict__ Wv,
        unsigned short* __restrict__ wb) {
    int idx = blockIdx.x * 256 + threadIdx.x;   // 196608 float4 chunks
    const float* src = (idx < 65536) ? Wq : (idx < 131072) ? Wk : Wv;
    int loc = idx & 65535;
    float4 f = *(const float4*)(src + (size_t)loc * 4);
    ushort4 o;
    o.x = f2b(f.x); o.y = f2b(f.y); o.z = f2b(f.z); o.w = f2b(f.w);
    *(ushort4*)(wb + (size_t)idx * 4) = o;
}

// ---------------------------------------------------------------------------
// QKV projection: C = xn @ W^T, bf16 MFMA, 128x128 tile, BK=64.
// z==2 (V) writes transposed: vt[b][h][c][t].
// ---------------------------------------------------------------------------
__global__ __launch_bounds__(256) void qkv_gemm(const unsigned short* __restrict__ xb,
        const unsigned short* __restrict__ wb,
        unsigned short* __restrict__ qb, unsigned short* __restrict__ kb,
        unsigned short* __restrict__ vtb) {
    const int z  = blockIdx.z;
    const int bm = blockIdx.y * 128;
    const int bn = blockIdx.x * 128;
    const int t  = threadIdx.x;
    const int w = t >> 6, l = t & 63, lr = l & 15, lg = l >> 4;
    const int wm = w >> 1, wn = w & 1;

    __shared__ __attribute__((aligned(16))) unsigned short As[128 * 64];
    __shared__ __attribute__((aligned(16))) unsigned short Bs[128 * 64];
    const unsigned short* Wp = wb + (size_t)z * ND * ND;

    f32x4 acc[4][4];
    #pragma unroll
    for (int i = 0; i < 4; ++i)
        #pragma unroll
        for (int j = 0; j < 4; ++j) acc[i][j] = (f32x4){0.f, 0.f, 0.f, 0.f};

    for (int k0 = 0; k0 < ND; k0 += 64) {
        __syncthreads();
        #pragma unroll
        for (int i = 0; i < 4; ++i) {
            int ch = i * 256 + t;
            int r = ch >> 3, c16 = ch & 7;
            gload_lds16(xb + (size_t)(bm + r) * ND + k0 + c16 * 8, (char*)As + ch * 16);
            gload_lds16(Wp + (size_t)(bn + r) * ND + k0 + c16 * 8, (char*)Bs + ch * 16);
        }
        __syncthreads();
        #pragma unroll
        for (int ks = 0; ks < 2; ++ks) {
            bf16x8 af[4], bfr[4];
            #pragma unroll
            for (int mf = 0; mf < 4; ++mf)
                af[mf] = *(const bf16x8*)((const char*)As + (wm*64 + mf*16 + lr)*128 + ks*64 + lg*16);
            #pragma unroll
            for (int nf = 0; nf < 4; ++nf)
                bfr[nf] = *(const bf16x8*)((const char*)Bs + (wn*64 + nf*16 + lr)*128 + ks*64 + lg*16);
            #pragma unroll
            for (int mf = 0; mf < 4; ++mf)
                #pragma unroll
                for (int nf = 0; nf < 4; ++nf)
                    acc[mf][nf] = __builtin_amdgcn_mfma_f32_16x16x32_bf16(
                        af[mf], bfr[nf], acc[mf][nf], 0, 0, 0);
        }
    }

    if (z < 2) {
        unsigned short* outp = (z == 0) ? qb : kb;
        #pragma unroll
        for (int mf = 0; mf < 4; ++mf)
            #pragma unroll
            for (int r = 0; r < 4; ++r) {
                int grow = bm + wm*64 + mf*16 + lg*4 + r;
                #pragma unroll
                for (int nf = 0; nf < 4; ++nf) {
                    int gcol = bn + wn*64 + nf*16 + lr;
                    outp[(size_t)grow * ND + gcol] = f2b(acc[mf][nf][r]);
                }
            }
    } else {
        #pragma unroll
        for (int mf = 0; mf < 4; ++mf)
            #pragma unroll
            for (int r = 0; r < 4; ++r) {
                int grow = bm + wm*64 + mf*16 + lg*4 + r;
                int bb = grow >> 11, tt = grow & 2047;
                #pragma unroll
                for (int nf = 0; nf < 4; ++nf) {
                    int gcol = bn + wn*64 + nf*16 + lr;
                    int h = gcol >> 6, c = gcol & 63;
                    vtb[((size_t)(bb * NH + h) * NC + c) * NT + tt] = f2b(acc[mf][nf][r]);
                }
            }
    }
}

// ---------------------------------------------------------------------------
// Flash attention, bf16 MFMA.  Block = 128 q-rows x (b,h), 4 waves.
// K tile [64 keys][64 c], Vt tile [64 c][64 keys] in LDS, XOR-swizzled via
// pre-swizzled global_load_lds source (rule 21).  P via wave-private LDS.
// ---------------------------------------------------------------------------
__global__ __launch_bounds__(256) void attn_kernel(
        const unsigned short* __restrict__ qb, const unsigned short* __restrict__ kb,
        const unsigned short* __restrict__ vtb,
        const float* __restrict__ x, const float* __restrict__ emb,
        float* __restrict__ out) {
    const int b = blockIdx.z, h = blockIdx.y, q0 = blockIdx.x * 128;
    const int t = threadIdx.x;
    const int w = t >> 6, l = t & 63, lr = l & 15, lg = l >> 4;

    __shared__ __attribute__((aligned(16))) unsigned short Ks[64 * 64];
    __shared__ __attribute__((aligned(16))) unsigned short Vs[64 * 64];
    __shared__ __attribute__((aligned(16))) unsigned short Ps[4 * 32 * 64];

    // Q fragments in registers: rows q0 + w*32 + rb*16 + lr, k = ks*32+lg*8
    bf16x8 aq[2][2];
    #pragma unroll
    for (int rb = 0; rb < 2; ++rb)
        #pragma unroll
        for (int ks = 0; ks < 2; ++ks)
            aq[rb][ks] = *(const bf16x8*)(qb +
                (size_t)(b*NT + q0 + w*32 + rb*16 + lr) * ND + h*NC + ks*32 + lg*8);

    f32x4 o[2][4];
    float m_i[2][4], l_i[2][4];
    #pragma unroll
    for (int rb = 0; rb < 2; ++rb) {
        #pragma unroll
        for (int cb = 0; cb < 4; ++cb) o[rb][cb] = (f32x4){0.f, 0.f, 0.f, 0.f};
        #pragma unroll
        for (int r = 0; r < 4; ++r) { m_i[rb][r] = -1e30f; l_i[rb][r] = 0.f; }
    }

    const size_t kbase = (size_t)(b * NT) * ND + h * NC;
    const size_t vbase = (size_t)(b * NH + h) * NC * NT;

    for (int kt = 0; kt < NT; kt += 64) {
        __syncthreads();
        #pragma unroll
        for (int i = 0; i < 2; ++i) {
            int ch = i * 256 + t;
            int r = ch >> 3, c16 = ch & 7;
            int c16s = c16 ^ (r & 7);           // pre-swizzled source chunk
            gload_lds16(kb + kbase + (size_t)(kt + r) * ND + c16s * 8, (char*)Ks + ch * 16);
            gload_lds16(vtb + vbase + (size_t)r * NT + kt + c16s * 8, (char*)Vs + ch * 16);
        }
        __syncthreads();

        // S = Q K^T (raw, scale folded into exp2)
        f32x4 s[2][4];
        #pragma unroll
        for (int rb = 0; rb < 2; ++rb)
            #pragma unroll
            for (int cb = 0; cb < 4; ++cb) s[rb][cb] = (f32x4){0.f, 0.f, 0.f, 0.f};
        #pragma unroll
        for (int ks = 0; ks < 2; ++ks) {
            bf16x8 kf[4];
            #pragma unroll
            for (int cb = 0; cb < 4; ++cb) {
                int row = cb * 16 + lr;
                int c16 = (ks * 4 + lg) ^ (row & 7);
                kf[cb] = *(const bf16x8*)((const char*)Ks + row * 128 + c16 * 16);
            }
            #pragma unroll
            for (int rb = 0; rb < 2; ++rb)
                #pragma unroll
                for (int cb = 0; cb < 4; ++cb)
                    s[rb][cb] = __builtin_amdgcn_mfma_f32_16x16x32_bf16(
                        aq[rb][ks], kf[cb], s[rb][cb], 0, 0, 0);
        }

        // online softmax in D-layout (row = rb*16 + lg*4 + r, col = cb*16 + lr)
        #pragma unroll
        for (int rb = 0; rb < 2; ++rb)
            #pragma unroll
            for (int r = 0; r < 4; ++r) {
                float tm = fmaxf(fmaxf(s[rb][0][r], s[rb][1][r]),
                                 fmaxf(s[rb][2][r], s[rb][3][r]));
                tm = fmaxf(tm, __shfl_xor(tm, 1));
                tm = fmaxf(tm, __shfl_xor(tm, 2));
                tm = fmaxf(tm, __shfl_xor(tm, 4));
                tm = fmaxf(tm, __shfl_xor(tm, 8));
                float nm = fmaxf(m_i[rb][r], tm);
                float f = __builtin_amdgcn_exp2f((m_i[rb][r] - nm) * SCL);
                m_i[rb][r] = nm;
                float ts = 0.f;
                int prow = rb * 16 + lg * 4 + r;
                #pragma unroll
                for (int cb = 0; cb < 4; ++cb) {
                    float p = __builtin_amdgcn_exp2f((s[rb][cb][r] - nm) * SCL);
                    ts += p;
                    o[rb][cb][r] *= f;
                    int colb = (cb * 16 + lr) * 2;
                    int sbyt = prow * 128 + ((((colb >> 4)) ^ (prow & 7)) << 4) + (colb & 15);
                    *(unsigned short*)((char*)Ps + w * 4096 + sbyt) = f2b(p);
                }
                ts += __shfl_xor(ts, 1);
                ts += __shfl_xor(ts, 2);
                ts += __shfl_xor(ts, 4);
                ts += __shfl_xor(ts, 8);
                l_i[rb][r] = l_i[rb][r] * f + ts;
            }

        __builtin_amdgcn_wave_barrier();
        asm volatile("s_waitcnt lgkmcnt(0)" ::: "memory");
        __builtin_amdgcn_sched_barrier(0);

        // O += P V : A = P rows (q), B = Vt rows (c), contract keys
        #pragma unroll
        for (int ks = 0; ks < 2; ++ks) {
            bf16x8 pa[2], vf[4];
            #pragma unroll
            for (int rb = 0; rb < 2; ++rb) {
                int prow = rb * 16 + lr;
                int c16 = (ks * 4 + lg) ^ (prow & 7);
                pa[rb] = *(const bf16x8*)((const char*)Ps + w * 4096 + prow * 128 + c16 * 16);
            }
            #pragma unroll
            for (int cb = 0; cb < 4; ++cb) {
                int vrow = cb * 16 + lr;
                int c16 = (ks * 4 + lg) ^ (vrow & 7);
                vf[cb] = *(const bf16x8*)((const char*)Vs + vrow * 128 + c16 * 16);
            }
            #pragma unroll
            for (int rb = 0; rb < 2; ++rb)
                #pragma unroll
                for (int cb = 0; cb < 4; ++cb)
                    o[rb][cb] = __builtin_amdgcn_mfma_f32_16x16x32_bf16(
                        pa[rb], vf[cb], o[rb][cb], 0, 0, 0);
        }
    }

    // epilogue: out = x + emb + O/l
    #pragma unroll
    for (int rb = 0; rb < 2; ++rb)
        #pragma unroll
        for (int r = 0; r < 4; ++r) {
            int grow = q0 + w*32 + rb*16 + lg*4 + r;
            float inv = 1.0f / l_i[rb][r];
            #pragma unroll
            for (int cb = 0; cb < 4; ++cb) {
                int gcol = h * NC + cb * 16 + lr;
                size_t idx = (size_t)(b * NT + grow) * ND + gcol;
                out[idx] = x[idx] + emb[b * ND + gcol] + o[rb][cb][r] * inv;
            }
        }
}

// ---------------------------------------------------------------------------
extern "C" void kernel_launch(void* const* d_in, const int* in_sizes, int n_in,
                              void* d_out, int out_size, void* d_ws, size_t ws_size,
                              hipStream_t stream) {
    const float* x     = (const float*)d_in[0];
    const float* emb   = (const float*)d_in[1];
    const float* Wq    = (const float*)d_in[2];
    const float* Wk    = (const float*)d_in[3];
    const float* Wv    = (const float*)d_in[4];
    const float* gamma = (const float*)d_in[5];
    const float* beta  = (const float*)d_in[6];
    float* out = (float*)d_out;

    unsigned short* xbb = (unsigned short*)d_ws;                 // 8 MB
    unsigned short* wb  = xbb + (size_t)NM * ND;                 // 1.5 MB
    unsigned short* qbb = wb + (size_t)3 * ND * ND;              // 8 MB
    unsigned short* kbb = qbb + (size_t)NM * ND;                 // 8 MB
    unsigned short* vtb = kbb + (size_t)NM * ND;                 // 8 MB

    ln_kernel<<<NM, 256, 0, stream>>>(x, gamma, beta, xbb);
    wconv_kernel<<<768, 256, 0, stream>>>(Wq, Wk, Wv, wb);
    qkv_gemm<<<dim3(4, 64, 3), 256, 0, stream>>>(xbb, wb, qbb, kbb, vtb);
    attn_kernel<<<dim3(16, NH, NB), 256, 0, stream>>>(qbb, kbb, vtb, x, emb, out);
}

// Round 3
// 111.160 us; speedup vs baseline: 9.4928x; 1.4108x over previous
//
#include <hip/hip_runtime.h>
#include <math.h>

#define NB 4
#define NT 2048
#define ND 512
#define NH 8
#define NC 64
#define NM (NB*NT)
#define LN_EPS 1e-5f
#define SCL 0.18033688f   // (1/sqrt(64)) * log2(e)

typedef __attribute__((ext_vector_type(8))) short bf16x8;
typedef __attribute__((ext_vector_type(4))) float f32x4;
typedef __attribute__((ext_vector_type(16))) float f32x16;
typedef __attribute__((ext_vector_type(4))) unsigned int u32x4;

__device__ inline unsigned short f2b(float f) {
    unsigned int u = __builtin_bit_cast(unsigned int, f);
    u += 0x7FFFu + ((u >> 16) & 1u);
    return (unsigned short)(u >> 16);
}
__device__ inline float b2f(unsigned short u) {
    return __builtin_bit_cast(float, (unsigned int)u << 16);
}
__device__ inline unsigned cvtpk(float lo, float hi) {
    unsigned r;
    asm("v_cvt_pk_bf16_f32 %0, %1, %2" : "=v"(r) : "v"(lo), "v"(hi));
    return r;
}
__device__ inline void gload_lds16(const void* g, void* l) {
    __builtin_amdgcn_global_load_lds(
        (__attribute__((address_space(1))) void*)g,
        (__attribute__((address_space(3))) void*)l, 16, 0, 0);
}

// ---------------------------------------------------------------------------
// LayerNorm -> bf16 xn.
// ---------------------------------------------------------------------------
__global__ __launch_bounds__(256) void ln_kernel(const float* __restrict__ x,
        const float* __restrict__ gamma, const float* __restrict__ beta,
        unsigned short* __restrict__ xb) {
    const int row = blockIdx.x;
    const float* xr = x + (size_t)row * ND;
    const int t = threadIdx.x;

    float2 v = *(const float2*)(xr + 2*t);
    float s  = v.x + v.y;
    float ss = v.x*v.x + v.y*v.y;
    #pragma unroll
    for (int off = 1; off < 64; off <<= 1) {
        s  += __shfl_xor(s, off);
        ss += __shfl_xor(ss, off);
    }
    __shared__ float sb[4], ssb[4];
    if ((t & 63) == 0) { sb[t >> 6] = s; ssb[t >> 6] = ss; }
    __syncthreads();
    s  = sb[0] + sb[1] + sb[2] + sb[3];
    ss = ssb[0] + ssb[1] + ssb[2] + ssb[3];

    const float mu   = s * (1.0f / ND);
    const float var  = ss * (1.0f / ND) - mu * mu;
    const float rstd = rsqrtf(var + LN_EPS);

    float2 g  = *(const float2*)(gamma + 2*t);
    float2 be = *(const float2*)(beta + 2*t);
    ushort2 o;
    o.x = f2b((v.x - mu) * rstd * g.x + be.x);
    o.y = f2b((v.y - mu) * rstd * g.y + be.y);
    *(ushort2*)(xb + (size_t)row * ND + 2*t) = o;
}

// ---------------------------------------------------------------------------
// W fp32 -> bf16
// ---------------------------------------------------------------------------
__global__ __launch_bounds__(256) void wconv_kernel(const float* __restrict__ Wq,
        const float* __restrict__ Wk, const float* __restrict__ Wv,
        unsigned short* __restrict__ wb) {
    int idx = blockIdx.x * 256 + threadIdx.x;
    const float* src = (idx < 65536) ? Wq : (idx < 131072) ? Wk : Wv;
    int loc = idx & 65535;
    float4 f = *(const float4*)(src + (size_t)loc * 4);
    ushort4 o;
    o.x = f2b(f.x); o.y = f2b(f.y); o.z = f2b(f.z); o.w = f2b(f.w);
    *(ushort4*)(wb + (size_t)idx * 4) = o;
}

// ---------------------------------------------------------------------------
// QKV projection (unchanged from round 2): 128x128 tile, BK=64, bf16 MFMA.
// z==2 (V) writes transposed vt[b][h][c][t].
// ---------------------------------------------------------------------------
__global__ __launch_bounds__(256) void qkv_gemm(const unsigned short* __restrict__ xb,
        const unsigned short* __restrict__ wb,
        unsigned short* __restrict__ qb, unsigned short* __restrict__ kb,
        unsigned short* __restrict__ vtb) {
    const int z  = blockIdx.z;
    const int bm = blockIdx.y * 128;
    const int bn = blockIdx.x * 128;
    const int t  = threadIdx.x;
    const int w = t >> 6, l = t & 63, lr = l & 15, lg = l >> 4;
    const int wm = w >> 1, wn = w & 1;

    __shared__ __attribute__((aligned(16))) unsigned short As[128 * 64];
    __shared__ __attribute__((aligned(16))) unsigned short Bs[128 * 64];
    const unsigned short* Wp = wb + (size_t)z * ND * ND;

    f32x4 acc[4][4];
    #pragma unroll
    for (int i = 0; i < 4; ++i)
        #pragma unroll
        for (int j = 0; j < 4; ++j) acc[i][j] = (f32x4){0.f, 0.f, 0.f, 0.f};

    for (int k0 = 0; k0 < ND; k0 += 64) {
        __syncthreads();
        #pragma unroll
        for (int i = 0; i < 4; ++i) {
            int ch = i * 256 + t;
            int r = ch >> 3, c16 = ch & 7;
            gload_lds16(xb + (size_t)(bm + r) * ND + k0 + c16 * 8, (char*)As + ch * 16);
            gload_lds16(Wp + (size_t)(bn + r) * ND + k0 + c16 * 8, (char*)Bs + ch * 16);
        }
        __syncthreads();
        #pragma unroll
        for (int ks = 0; ks < 2; ++ks) {
            bf16x8 af[4], bfr[4];
            #pragma unroll
            for (int mf = 0; mf < 4; ++mf)
                af[mf] = *(const bf16x8*)((const char*)As + (wm*64 + mf*16 + lr)*128 + ks*64 + lg*16);
            #pragma unroll
            for (int nf = 0; nf < 4; ++nf)
                bfr[nf] = *(const bf16x8*)((const char*)Bs + (wn*64 + nf*16 + lr)*128 + ks*64 + lg*16);
            #pragma unroll
            for (int mf = 0; mf < 4; ++mf)
                #pragma unroll
                for (int nf = 0; nf < 4; ++nf)
                    acc[mf][nf] = __builtin_amdgcn_mfma_f32_16x16x32_bf16(
                        af[mf], bfr[nf], acc[mf][nf], 0, 0, 0);
        }
    }

    if (z < 2) {
        unsigned short* outp = (z == 0) ? qb : kb;
        #pragma unroll
        for (int mf = 0; mf < 4; ++mf)
            #pragma unroll
            for (int r = 0; r < 4; ++r) {
                int grow = bm + wm*64 + mf*16 + lg*4 + r;
                #pragma unroll
                for (int nf = 0; nf < 4; ++nf) {
                    int gcol = bn + wn*64 + nf*16 + lr;
                    outp[(size_t)grow * ND + gcol] = f2b(acc[mf][nf][r]);
                }
            }
    } else {
        #pragma unroll
        for (int mf = 0; mf < 4; ++mf)
            #pragma unroll
            for (int r = 0; r < 4; ++r) {
                int grow = bm + wm*64 + mf*16 + lg*4 + r;
                int bb = grow >> 11, tt = grow & 2047;
                #pragma unroll
                for (int nf = 0; nf < 4; ++nf) {
                    int gcol = bn + wn*64 + nf*16 + lr;
                    int h = gcol >> 6, c = gcol & 63;
                    vtb[((size_t)(bb * NH + h) * NC + c) * NT + tt] = f2b(acc[mf][nf][r]);
                }
            }
    }
}

// ---------------------------------------------------------------------------
// Flash attention, swapped 32x32x16 structure, KV-split by 2.
// Block = 4 waves x 32 q-rows; each lane owns one query's scores (16 regs +
// partner lane l^32).  Softmax fully in-register; P -> MFMA-A fragments via
// v_cvt_pk_bf16_f32 + shfl_xor(32) half-swap.  Defer-max THR=8.
// Writes bf16 partial O^T + (m,l) per query; combine kernel merges halves.
// ---------------------------------------------------------------------------
__global__ __launch_bounds__(256, 3) void attn_kernel(
        const unsigned short* __restrict__ qb, const unsigned short* __restrict__ kb,
        const unsigned short* __restrict__ vtb,
        unsigned short* __restrict__ Opart, float* __restrict__ mlb) {
    const int b = blockIdx.z, h = blockIdx.y;
    const int qt = blockIdx.x & 15, half = blockIdx.x >> 4;
    const int koff = half * (NT / 2);
    const int t = threadIdx.x;
    const int w = t >> 6, l = t & 63;
    const int q32 = l & 31, hi = l >> 5;
    const int bh = b * NH + h;

    __shared__ __attribute__((aligned(16))) unsigned short Ks[64 * 64];
    __shared__ __attribute__((aligned(16))) unsigned short Vs[64 * 64];

    // Q fragments: lane owns query row qrow; k = cs*16 + hi*8 + j
    const int qrow = qt * 128 + w * 32 + q32;
    bf16x8 aq[4];
    #pragma unroll
    for (int cs = 0; cs < 4; ++cs)
        aq[cs] = *(const bf16x8*)(qb + (size_t)(b*NT + qrow) * ND + h*NC + cs*16 + hi*8);

    f32x16 oa[2];
    #pragma unroll
    for (int ct = 0; ct < 2; ++ct)
        #pragma unroll
        for (int r = 0; r < 16; ++r) oa[ct][r] = 0.f;
    float m = -1e30f, li = 0.f;

    const size_t kbase = (size_t)(b * NT) * ND + h * NC;
    const size_t vbase = (size_t)bh * NC * NT;

    for (int kt = 0; kt < NT/2; kt += 64) {
        __syncthreads();
        #pragma unroll
        for (int i = 0; i < 2; ++i) {
            int ch = i * 256 + t;
            int r = ch >> 3, c16 = ch & 7;
            int c16s = c16 ^ (r & 7);
            gload_lds16(kb + kbase + (size_t)(koff + kt + r) * ND + c16s * 8, (char*)Ks + ch * 16);
            gload_lds16(vtb + vbase + (size_t)r * NT + koff + kt + c16s * 8, (char*)Vs + ch * 16);
        }
        __syncthreads();

        // S^T = K Q^T : lane's query scores for 64 keys (2 subtiles of 32)
        f32x16 sa[2];
        #pragma unroll
        for (int ks = 0; ks < 2; ++ks) {
            #pragma unroll
            for (int r = 0; r < 16; ++r) sa[ks][r] = 0.f;
            const int kr = ks * 32 + q32;
            #pragma unroll
            for (int cs = 0; cs < 4; ++cs) {
                int chunk = (cs*2 + hi) ^ (kr & 7);
                bf16x8 kf = *(const bf16x8*)((const char*)Ks + kr*128 + chunk*16);
                sa[ks] = __builtin_amdgcn_mfma_f32_32x32x16_bf16(kf, aq[cs], sa[ks], 0, 0, 0);
            }
        }

        // tile max (in-register tree + partner lane)
        float mx0 = fmaxf(sa[0][0], sa[1][0]), mx1 = fmaxf(sa[0][1], sa[1][1]);
        float mx2 = fmaxf(sa[0][2], sa[1][2]), mx3 = fmaxf(sa[0][3], sa[1][3]);
        #pragma unroll
        for (int r = 4; r < 16; r += 4) {
            mx0 = fmaxf(mx0, fmaxf(sa[0][r+0], sa[1][r+0]));
            mx1 = fmaxf(mx1, fmaxf(sa[0][r+1], sa[1][r+1]));
            mx2 = fmaxf(mx2, fmaxf(sa[0][r+2], sa[1][r+2]));
            mx3 = fmaxf(mx3, fmaxf(sa[0][r+3], sa[1][r+3]));
        }
        float tm = fmaxf(fmaxf(mx0, mx1), fmaxf(mx2, mx3));
        tm = fmaxf(tm, __shfl_xor(tm, 32));

        // defer-max: only rescale when some query's max grew past THR=8 (exp2 dom)
        if (__any((tm - m) * SCL > 8.0f)) {
            float nm = fmaxf(m, tm);
            float f = __builtin_amdgcn_exp2f((m - nm) * SCL);
            m = nm;
            li *= f;
            #pragma unroll
            for (int ct = 0; ct < 2; ++ct)
                #pragma unroll
                for (int r = 0; r < 16; ++r) oa[ct][r] *= f;
        }

        // P = exp2((s - m)*SCL), in place; 4-way sum tree
        float s0 = 0.f, s1 = 0.f, s2 = 0.f, s3 = 0.f;
        #pragma unroll
        for (int ks = 0; ks < 2; ++ks)
            #pragma unroll
            for (int r = 0; r < 16; r += 4) {
                float p0 = __builtin_amdgcn_exp2f((sa[ks][r+0] - m) * SCL);
                float p1 = __builtin_amdgcn_exp2f((sa[ks][r+1] - m) * SCL);
                float p2 = __builtin_amdgcn_exp2f((sa[ks][r+2] - m) * SCL);
                float p3 = __builtin_amdgcn_exp2f((sa[ks][r+3] - m) * SCL);
                sa[ks][r+0] = p0; sa[ks][r+1] = p1; sa[ks][r+2] = p2; sa[ks][r+3] = p3;
                s0 += p0; s1 += p1; s2 += p2; s3 += p3;
            }
        float ts = (s0 + s1) + (s2 + s3);
        ts += __shfl_xor(ts, 32);
        li += ts;

        // build PV B-fragments: cvt_pk pairs + half-swap with partner lane
        bf16x8 pa[4];
        #pragma unroll
        for (int ks = 0; ks < 2; ++ks)
            #pragma unroll
            for (int h2 = 0; h2 < 2; ++h2) {
                unsigned c01 = cvtpk(sa[ks][8*h2+0], sa[ks][8*h2+1]);
                unsigned c23 = cvtpk(sa[ks][8*h2+2], sa[ks][8*h2+3]);
                unsigned c45 = cvtpk(sa[ks][8*h2+4], sa[ks][8*h2+5]);
                unsigned c67 = cvtpk(sa[ks][8*h2+6], sa[ks][8*h2+7]);
                unsigned x01 = (unsigned)__shfl_xor((int)c01, 32);
                unsigned x23 = (unsigned)__shfl_xor((int)c23, 32);
                unsigned x45 = (unsigned)__shfl_xor((int)c45, 32);
                unsigned x67 = (unsigned)__shfl_xor((int)c67, 32);
                u32x4 wv;
                wv.x = hi ? x45 : c01;
                wv.y = hi ? x67 : c23;
                wv.z = hi ? c45 : x01;
                wv.w = hi ? c67 : x23;
                pa[ks*2 + h2] = __builtin_bit_cast(bf16x8, wv);
            }

        // O^T += V^T P^T
        #pragma unroll
        for (int j = 0; j < 4; ++j)
            #pragma unroll
            for (int ct = 0; ct < 2; ++ct) {
                int vr = ct * 32 + q32;
                int chunk = (j*2 + hi) ^ (vr & 7);
                bf16x8 vf = *(const bf16x8*)((const char*)Vs + vr*128 + chunk*16);
                oa[ct] = __builtin_amdgcn_mfma_f32_32x32x16_bf16(vf, pa[j], oa[ct], 0, 0, 0);
            }
    }

    // write bf16 partial O (layout [half][bh][q][c]) and (m, l)
    const int qq = qt * 128 + w * 32 + q32;
    size_t obase = ((size_t)(half * 32 + bh) * 2048 + qq) * 64;
    #pragma unroll
    for (int ct = 0; ct < 2; ++ct)
        #pragma unroll
        for (int g = 0; g < 4; ++g) {
            ushort4 ov;
            ov.x = f2b(oa[ct][4*g+0]); ov.y = f2b(oa[ct][4*g+1]);
            ov.z = f2b(oa[ct][4*g+2]); ov.w = f2b(oa[ct][4*g+3]);
            *(ushort4*)(Opart + obase + 32*ct + 8*g + 4*hi) = ov;
        }
    if (hi == 0)
        *(float2*)(mlb + ((size_t)(half * 32 + bh) * 2048 + qq) * 2) = make_float2(m, li);
}

// ---------------------------------------------------------------------------
// Combine the two KV-halves + fused residual epilogue.
// ---------------------------------------------------------------------------
__global__ __launch_bounds__(256) void combine_kernel(
        const unsigned short* __restrict__ Opart, const float* __restrict__ mlb,
        const float* __restrict__ x, const float* __restrict__ emb,
        float* __restrict__ out) {
    int tid = blockIdx.x * 256 + threadIdx.x;   // 1M threads, 4 c each
    int qi = tid >> 4;                          // bh*2048 + qq
    int c4 = (tid & 15) * 4;
    int bh = qi >> 11, qq = qi & 2047;
    int b = bh >> 3, h = bh & 7;

    float2 ml0 = *(const float2*)(mlb + (size_t)qi * 2);
    float2 ml1 = *(const float2*)(mlb + ((size_t)65536 + qi) * 2);
    float M = fmaxf(ml0.x, ml1.x);
    float f0 = __builtin_amdgcn_exp2f((ml0.x - M) * SCL);
    float f1 = __builtin_amdgcn_exp2f((ml1.x - M) * SCL);
    float inv = 1.0f / (ml0.y * f0 + ml1.y * f1);

    ushort4 u0 = *(const ushort4*)(Opart + (size_t)qi * 64 + c4);
    ushort4 u1 = *(const ushort4*)(Opart + ((size_t)65536 + qi) * 64 + c4);

    size_t oidx = ((size_t)(b * NT) + qq) * ND + h * NC + c4;
    float4 xv = *(const float4*)(x + oidx);
    float4 ev = *(const float4*)(emb + (size_t)b * ND + h * NC + c4);
    float4 r;
    r.x = xv.x + ev.x + (b2f(u0.x) * f0 + b2f(u1.x) * f1) * inv;
    r.y = xv.y + ev.y + (b2f(u0.y) * f0 + b2f(u1.y) * f1) * inv;
    r.z = xv.z + ev.z + (b2f(u0.z) * f0 + b2f(u1.z) * f1) * inv;
    r.w = xv.w + ev.w + (b2f(u0.w) * f0 + b2f(u1.w) * f1) * inv;
    *(float4*)(out + oidx) = r;
}

// ---------------------------------------------------------------------------
extern "C" void kernel_launch(void* const* d_in, const int* in_sizes, int n_in,
                              void* d_out, int out_size, void* d_ws, size_t ws_size,
                              hipStream_t stream) {
    const float* x     = (const float*)d_in[0];
    const float* emb   = (const float*)d_in[1];
    const float* Wq    = (const float*)d_in[2];
    const float* Wk    = (const float*)d_in[3];
    const float* Wv    = (const float*)d_in[4];
    const float* gamma = (const float*)d_in[5];
    const float* beta  = (const float*)d_in[6];
    float* out = (float*)d_out;

    // ws layout: qbb|kbb|vtb (24MB, live through attn), then a region that is
    // xbb+wb during LN/GEMM and Opart+mlb during attn/combine (lifetimes disjoint).
    unsigned short* qbb = (unsigned short*)d_ws;
    unsigned short* kbb = qbb + (size_t)NM * ND;
    unsigned short* vtb = kbb + (size_t)NM * ND;
    unsigned short* xbb = vtb + (size_t)NM * ND;
    unsigned short* wb  = xbb + (size_t)NM * ND;
    unsigned short* Opart = xbb;                               // 2*65536*64 bf16 = 16.8MB
    float* mlb = (float*)(xbb + (size_t)2 * 65536 * 64);       // 2*65536 float2 = 1MB

    ln_kernel<<<NM, 256, 0, stream>>>(x, gamma, beta, xbb);
    wconv_kernel<<<768, 256, 0, stream>>>(Wq, Wk, Wv, wb);
    qkv_gemm<<<dim3(4, 64, 3), 256, 0, stream>>>(xbb, wb, qbb, kbb, vtb);
    attn_kernel<<<dim3(32, NH, NB), 256, 0, stream>>>(qbb, kbb, vtb, Opart, mlb);
    combine_kernel<<<4096, 256, 0, stream>>>(Opart, mlb, x, emb, out);
}